// Round 1
// baseline (1251.494 us; speedup 1.0000x reference)
//
#include <hip/hip_runtime.h>
#include <math.h>

namespace {

constexpr int B  = 1024;
constexpr int M  = 65536;
constexpr int D  = 384;
constexpr int H  = 384;
constexpr int KK = 5;      // retrieval_k
constexpr int NC = 64;     // number of M chunks for partial top-k
constexpr int CHUNK = M / NC;   // 1024
constexpr float FEPS = 1e-8f;

constexpr int BQ = 64;     // query tile
constexpr int BM = 64;     // mem tile
constexpr int KT = 16;     // K tile

// sorted-descending top-5 insert; fully unrolled, static indices -> registers.
// Strict '>' keeps earlier (lower-index) entries ahead on ties, matching lax.top_k.
__device__ __forceinline__ void insert5(float (&vv)[KK], int (&ii)[KK], float v, int ix) {
  if (v > vv[KK-1]) {
    vv[KK-1] = v; ii[KK-1] = ix;
#pragma unroll
    for (int s = KK-1; s > 0; --s) {
      if (vv[s] > vv[s-1]) {
        float tv = vv[s]; vv[s] = vv[s-1]; vv[s-1] = tv;
        int   ti = ii[s]; ii[s] = ii[s-1]; ii[s-1] = ti;
      }
    }
  }
}

// ---- center = mean(spatial_weights, axis=0) ----
__global__ void k_center(const float* __restrict__ sw, float* __restrict__ center) {
  int t = threadIdx.x;
  float sx = 0.f, sy = 0.f;
  for (int i = t; i < H; i += 64) { sx += sw[2*i]; sy += sw[2*i+1]; }
#pragma unroll
  for (int o = 32; o > 0; o >>= 1) { sx += __shfl_down(sx, o); sy += __shfl_down(sy, o); }
  if (t == 0) { center[0] = sx / (float)H; center[1] = sy / (float)H; }
}

// ---- per-mem-row L2 norm + spatial activation (one wave per row) ----
__global__ void k_memstats(const float* __restrict__ mem, const float* __restrict__ coords,
                           const float* __restrict__ center,
                           float* __restrict__ mn, float* __restrict__ act) {
  int wave = threadIdx.x >> 6, lane = threadIdx.x & 63;
  int m = blockIdx.x * 4 + wave;
  const float* row = mem + (size_t)m * D;
  float s = 0.f;
  for (int i = lane; i < D; i += 64) { float v = row[i]; s += v * v; }
#pragma unroll
  for (int o = 32; o > 0; o >>= 1) s += __shfl_down(s, o);
  if (lane == 0) {
    mn[m] = sqrtf(s);
    float dx = coords[2*m]   - center[0];
    float dy = coords[2*m+1] - center[1];
    act[m] = 1.0f / (1.0f + sqrtf(dx*dx + dy*dy));
  }
}

__global__ void k_qnorm(const float* __restrict__ q, float* __restrict__ qn) {
  int wave = threadIdx.x >> 6, lane = threadIdx.x & 63;
  int b = blockIdx.x * 4 + wave;
  const float* row = q + (size_t)b * D;
  float s = 0.f;
  for (int i = lane; i < D; i += 64) { float v = row[i]; s += v * v; }
#pragma unroll
  for (int o = 32; o > 0; o >>= 1) s += __shfl_down(s, o);
  if (lane == 0) qn[b] = sqrtf(s);
}

// ---- fused fp32 GEMM (query x mem^T) + cosine/activation + per-chunk top-5 ----
// grid: (B/BQ, NC); block 256 (16x16 threads, 4x4 micro-tile).
__global__ __launch_bounds__(256) void k_sim_topk(
    const float* __restrict__ q, const float* __restrict__ mem,
    const float* __restrict__ qn, const float* __restrict__ mn,
    const float* __restrict__ act,
    float* __restrict__ pvals, int* __restrict__ pidx) {
  // k-major tiles, row stride 68 floats: float4-aligned reads, 2-way-max bank aliasing
  __shared__ __align__(16) float As2[KT][68];
  __shared__ __align__(16) float Bs2[KT][68];
  __shared__ float mv [BQ][16*KK + 1];
  __shared__ int   mi2[BQ][16*KK + 1];

  int tid = threadIdx.x;
  int tx = tid & 15, ty = tid >> 4;
  int lrow = tid >> 2, lseg = (tid & 3) * 4;
  int qbase  = blockIdx.x * BQ;
  int mbase0 = blockIdx.y * CHUNK;

  const float* arow = q + (size_t)(qbase + lrow) * D + lseg;

  float t5v[4][KK]; int t5i[4][KK];
#pragma unroll
  for (int i = 0; i < 4; ++i)
#pragma unroll
    for (int s = 0; s < KK; ++s) { t5v[i][s] = -INFINITY; t5i[i][s] = -1; }

  float qns[4];
#pragma unroll
  for (int i = 0; i < 4; ++i) qns[i] = qn[qbase + ty*4 + i];

  for (int mi = 0; mi < CHUNK / BM; ++mi) {
    int mbase = mbase0 + mi * BM;
    const float* brow = mem + (size_t)(mbase + lrow) * D + lseg;
    float acc[4][4] = {};
    for (int kt = 0; kt < D; kt += KT) {
      float4 a4 = *(const float4*)(arow + kt);
      float4 b4 = *(const float4*)(brow + kt);
      As2[lseg+0][lrow] = a4.x; As2[lseg+1][lrow] = a4.y;
      As2[lseg+2][lrow] = a4.z; As2[lseg+3][lrow] = a4.w;
      Bs2[lseg+0][lrow] = b4.x; Bs2[lseg+1][lrow] = b4.y;
      Bs2[lseg+2][lrow] = b4.z; Bs2[lseg+3][lrow] = b4.w;
      __syncthreads();
#pragma unroll
      for (int k = 0; k < KT; ++k) {
        float4 a = *(const float4*)&As2[k][ty*4];
        float4 bb = *(const float4*)&Bs2[k][tx*4];
        float av[4] = {a.x, a.y, a.z, a.w};
        float bv[4] = {bb.x, bb.y, bb.z, bb.w};
#pragma unroll
        for (int i = 0; i < 4; ++i)
#pragma unroll
          for (int j = 0; j < 4; ++j)
            acc[i][j] += av[i] * bv[j];
      }
      __syncthreads();
    }
    float mnv[4], actv[4];
#pragma unroll
    for (int j = 0; j < 4; ++j) {
      mnv[j]  = mn [mbase + tx*4 + j];
      actv[j] = act[mbase + tx*4 + j];
    }
#pragma unroll
    for (int i = 0; i < 4; ++i)
#pragma unroll
      for (int j = 0; j < 4; ++j) {
        float v = acc[i][j] / fmaxf(qns[i] * mnv[j], FEPS) + actv[j];
        insert5(t5v[i], t5i[i], v, mbase + tx*4 + j);
      }
  }

  // block merge: 16 (tx) lists of 5 per query -> top-5 per (query, chunk)
#pragma unroll
  for (int i = 0; i < 4; ++i)
#pragma unroll
    for (int s = 0; s < KK; ++s) {
      mv [ty*4+i][tx*KK+s] = t5v[i][s];
      mi2[ty*4+i][tx*KK+s] = t5i[i][s];
    }
  __syncthreads();
  if (tid < BQ) {
    float bv[KK]; int bi[KK];
#pragma unroll
    for (int s = 0; s < KK; ++s) { bv[s] = -INFINITY; bi[s] = -1; }
    for (int c = 0; c < 16*KK; ++c) insert5(bv, bi, mv[tid][c], mi2[tid][c]);
    size_t off = ((size_t)(qbase + tid) * NC + blockIdx.y) * KK;
#pragma unroll
    for (int s = 0; s < KK; ++s) { pvals[off + s] = bv[s]; pidx[off + s] = bi[s]; }
  }
}

// ---- final top-5 merge across chunks (chunk-major scan => index-ascending on ties) ----
__global__ void k_topk_merge(const float* __restrict__ pvals, const int* __restrict__ pidx,
                             int* __restrict__ topk) {
  int b = blockIdx.x * blockDim.x + threadIdx.x;
  if (b >= B) return;
  const float* pv = pvals + (size_t)b * NC * KK;
  const int*   pi = pidx  + (size_t)b * NC * KK;
  float bv[KK]; int bi[KK];
#pragma unroll
  for (int s = 0; s < KK; ++s) { bv[s] = -INFINITY; bi[s] = -1; }
  for (int c = 0; c < NC*KK; ++c) insert5(bv, bi, pv[c], pi[c]);
#pragma unroll
  for (int s = 0; s < KK; ++s) topk[b*KK + s] = bi[s];
}

// ---- generic C[row,h] = act( A[row,:] . W[h,:] + bias[h] (+ add) ), K = 384 ----
// ACT: 0 none, 1 sigmoid, 2 tanh. AMODE: 0 plain rows, 1 gathered seq rows (B*6).
template<int ACT, int AMODE, int HASADD>
__global__ __launch_bounds__(256) void k_gemm384(
    const float* __restrict__ A, const float* __restrict__ memv,
    const int* __restrict__ topk,
    const float* __restrict__ W, const float* __restrict__ bias,
    const float* __restrict__ addv, int addstride, int addoff,
    float* __restrict__ C) {
  __shared__ __align__(16) float As2[KT][68];
  __shared__ __align__(16) float Bs2[KT][68];
  int tid = threadIdx.x, tx = tid & 15, ty = tid >> 4;
  int lrow = tid >> 2, lseg = (tid & 3) * 4;
  int rbase = blockIdx.x * 64, hbase = blockIdx.y * 64;

  const float* arow;
  if (AMODE == 0) {
    arow = A + (size_t)(rbase + lrow) * D + lseg;
  } else {
    int r = rbase + lrow; int b = r / 6, t = r - b * 6;
    arow = (t == 0) ? (A + (size_t)b * D + lseg)
                    : (memv + (size_t)topk[b*KK + t - 1] * D + lseg);
  }
  const float* wrow = W + (size_t)(hbase + lrow) * D + lseg;

  float acc[4][4] = {};
  for (int kt = 0; kt < D; kt += KT) {
    float4 a4 = *(const float4*)(arow + kt);
    float4 b4 = *(const float4*)(wrow + kt);
    As2[lseg+0][lrow] = a4.x; As2[lseg+1][lrow] = a4.y;
    As2[lseg+2][lrow] = a4.z; As2[lseg+3][lrow] = a4.w;
    Bs2[lseg+0][lrow] = b4.x; Bs2[lseg+1][lrow] = b4.y;
    Bs2[lseg+2][lrow] = b4.z; Bs2[lseg+3][lrow] = b4.w;
    __syncthreads();
#pragma unroll
    for (int k = 0; k < KT; ++k) {
      float4 a = *(const float4*)&As2[k][ty*4];
      float4 bb = *(const float4*)&Bs2[k][tx*4];
      float av[4] = {a.x, a.y, a.z, a.w};
      float bv[4] = {bb.x, bb.y, bb.z, bb.w};
#pragma unroll
      for (int i = 0; i < 4; ++i)
#pragma unroll
        for (int j = 0; j < 4; ++j)
          acc[i][j] += av[i] * bv[j];
    }
    __syncthreads();
  }
#pragma unroll
  for (int i = 0; i < 4; ++i) {
    int row = rbase + ty*4 + i;
    float vv[4];
#pragma unroll
    for (int j = 0; j < 4; ++j) {
      int h = hbase + tx*4 + j;
      float v = acc[i][j] + bias[h];
      if (HASADD) v += addv[(size_t)row * addstride + addoff + h];
      if (ACT == 1) v = 1.0f / (1.0f + expf(-v));
      else if (ACT == 2) v = tanhf(v);
      vv[j] = v;
    }
    float4 o; o.x = vv[0]; o.y = vv[1]; o.z = vv[2]; o.w = vv[3];
    *(float4*)(C + (size_t)row * H + hbase + tx*4) = o;
  }
}

// ---- h1 = tanh(x_0 + b_hh)  (h0 == 0) ----
__global__ void k_h0(const float* __restrict__ xp, const float* __restrict__ bhh,
                     float* __restrict__ hout) {
  int i = blockIdx.x * blockDim.x + threadIdx.x;
  if (i >= B*H) return;
  int b = i / H, h = i - b * H;
  hout[i] = tanhf(xp[(size_t)b * (6*H) + h] + bhh[h]);
}

// ---- out = gate*h + (1-gate)*direct, direct = xp[:,0,:] ----
__global__ void k_out(const float* __restrict__ gate, const float* __restrict__ hfin,
                      const float* __restrict__ xp, float* __restrict__ out) {
  int i = blockIdx.x * blockDim.x + threadIdx.x;
  if (i >= B*H) return;
  int b = i / H, h = i - b * H;
  float g = gate[i];
  out[i] = g * hfin[i] + (1.0f - g) * xp[(size_t)b * (6*H) + h];
}

} // namespace

extern "C" void kernel_launch(void* const* d_in, const int* in_sizes, int n_in,
                              void* d_out, int out_size, void* d_ws, size_t ws_size,
                              hipStream_t stream) {
  const float* query = (const float*)d_in[0];
  const float* memv  = (const float*)d_in[1];
  const float* coords= (const float*)d_in[2];
  const float* sw    = (const float*)d_in[3];
  const float* W_ih  = (const float*)d_in[4];
  const float* b_ih  = (const float*)d_in[5];
  const float* W_hh  = (const float*)d_in[6];
  const float* b_hh  = (const float*)d_in[7];
  const float* W_g   = (const float*)d_in[8];
  const float* b_g   = (const float*)d_in[9];
  float* out = (float*)d_out;

  char* p = (char*)d_ws;
  auto alloc = [&](size_t bytes) {
    char* r = p; p += (bytes + 255) & ~(size_t)255; return r;
  };
  float* center = (float*)alloc(2 * 4);
  float* mn     = (float*)alloc((size_t)M * 4);
  float* act    = (float*)alloc((size_t)M * 4);
  float* qn     = (float*)alloc((size_t)B * 4);
  float* pvals  = (float*)alloc((size_t)B * NC * KK * 4);
  int*   pidx   = (int*)  alloc((size_t)B * NC * KK * 4);
  int*   topk   = (int*)  alloc((size_t)B * KK * 4);
  float* xp     = (float*)alloc((size_t)B * 6 * H * 4);
  float* gate   = (float*)alloc((size_t)B * H * 4);
  float* hA     = (float*)alloc((size_t)B * H * 4);
  float* hB     = (float*)alloc((size_t)B * H * 4);

  k_center  <<<1, 64, 0, stream>>>(sw, center);
  k_memstats<<<M/4, 256, 0, stream>>>(memv, coords, center, mn, act);
  k_qnorm   <<<B/4, 256, 0, stream>>>(query, qn);
  k_sim_topk<<<dim3(B/BQ, NC), 256, 0, stream>>>(query, memv, qn, mn, act, pvals, pidx);
  k_topk_merge<<<(B + 255)/256, 256, 0, stream>>>(pvals, pidx, topk);

  // x_proj over gathered seq rows [B*6, H]
  k_gemm384<0,1,0><<<dim3(B*6/64, H/64), 256, 0, stream>>>(
      query, memv, topk, W_ih, b_ih, nullptr, 0, 0, xp);
  // gate = sigmoid(query @ W_g^T + b_g)
  k_gemm384<1,0,0><<<dim3(B/64, H/64), 256, 0, stream>>>(
      query, nullptr, nullptr, W_g, b_g, nullptr, 0, 0, gate);

  // RNN: h1 = tanh(x_0 + b_hh); then 5 recurrent steps
  k_h0<<<(B*H + 255)/256, 256, 0, stream>>>(xp, b_hh, hA);
  float* hcur = hA; float* hnxt = hB;
  for (int t = 1; t < 6; ++t) {
    k_gemm384<2,0,1><<<dim3(B/64, H/64), 256, 0, stream>>>(
        hcur, nullptr, nullptr, W_hh, b_hh, xp, 6*H, t*H, hnxt);
    float* tmp = hcur; hcur = hnxt; hnxt = tmp;
  }
  k_out<<<(B*H + 255)/256, 256, 0, stream>>>(gate, hcur, xp, out);
}

// Round 2
// 554.047 us; speedup vs baseline: 2.2588x; 2.2588x over previous
//
#include <hip/hip_runtime.h>
#include <math.h>

namespace {

typedef float f32x4 __attribute__((ext_vector_type(4)));
typedef short bf16x8 __attribute__((ext_vector_type(8)));

constexpr int B  = 1024;
constexpr int M  = 65536;
constexpr int D  = 384;
constexpr int H  = 384;
constexpr int KK = 5;
constexpr int NC = 64;          // chunks over M
constexpr int CHUNK = M / NC;   // 1024 mems per chunk (10-bit local idx)
constexpr float FEPS = 1e-8f;
constexpr int KT = 16;          // fp32 gemm384 K tile (RNN path)

__device__ __forceinline__ unsigned short f2bf(float x) {
  unsigned int u = __float_as_uint(x);
  unsigned int r = (u + 0x7FFFu + ((u >> 16) & 1u)) >> 16;   // RNE
  return (unsigned short)r;
}
__device__ __forceinline__ float bf2f(unsigned short h) {
  return __uint_as_float(((unsigned int)h) << 16);
}

__device__ __forceinline__ void async16(const unsigned short* g, unsigned short* l) {
  __builtin_amdgcn_global_load_lds(
      (const __attribute__((address_space(1))) unsigned int*)g,
      (__attribute__((address_space(3))) unsigned int*)l, 16, 0, 0);
}

// branchless sorted-descending insert of packed u32 keys
__device__ __forceinline__ void insert3b(unsigned int* k, unsigned int v) {
  unsigned int t0 = min(k[0], v); k[0] = max(k[0], v);
  unsigned int t1 = min(k[1], t0); k[1] = max(k[1], t0);
  k[2] = max(k[2], t1);
}
__device__ __forceinline__ void insert5b(unsigned int* k, unsigned int v) {
  unsigned int t0 = min(k[0], v); k[0] = max(k[0], v);
  unsigned int t1 = min(k[1], t0); k[1] = max(k[1], t0);
  unsigned int t2 = min(k[2], t1); k[2] = max(k[2], t1);
  unsigned int t3 = min(k[3], t2); k[3] = max(k[3], t2);
  k[4] = max(k[4], t3);
}

// ---- center = mean(spatial_weights, axis=0) ----
__global__ void k_center(const float* __restrict__ sw, float* __restrict__ center) {
  int t = threadIdx.x;
  float sx = 0.f, sy = 0.f;
  for (int i = t; i < H; i += 64) { sx += sw[2*i]; sy += sw[2*i+1]; }
#pragma unroll
  for (int o = 32; o > 0; o >>= 1) { sx += __shfl_down(sx, o); sy += __shfl_down(sy, o); }
  if (t == 0) { center[0] = sx / (float)H; center[1] = sy / (float)H; }
}

// ---- split normalized query into hi/lo bf16 (wave per row) ----
__global__ void k_prep_q(const float* __restrict__ q,
                         unsigned short* __restrict__ qh, unsigned short* __restrict__ ql) {
  int wv = threadIdx.x >> 6, lane = threadIdx.x & 63;
  int r = blockIdx.x * 4 + wv;
  float x[6]; float s = 0.f;
#pragma unroll
  for (int k = 0; k < 6; ++k) { x[k] = q[(size_t)r*D + lane + 64*k]; s += x[k]*x[k]; }
#pragma unroll
  for (int o = 32; o > 0; o >>= 1) s += __shfl_xor(s, o);
  float inv = 1.0f / sqrtf(s);
#pragma unroll
  for (int k = 0; k < 6; ++k) {
    float xv = x[k] * inv;
    unsigned short h = f2bf(xv);
    unsigned short l = f2bf(xv - bf2f(h));
    qh[(size_t)r*D + lane + 64*k] = h;
    ql[(size_t)r*D + lane + 64*k] = l;
  }
}

// ---- split mem rows + per-row stats (wave per row) ----
__global__ void k_prep_m(const float* __restrict__ mem, const float* __restrict__ coords,
                         const float* __restrict__ center,
                         unsigned short* __restrict__ mh, unsigned short* __restrict__ ml,
                         float2* __restrict__ f2a, float2* __restrict__ f2b) {
  int wv = threadIdx.x >> 6, lane = threadIdx.x & 63;
  int r = blockIdx.x * 4 + wv;
  float x[6]; float s = 0.f;
#pragma unroll
  for (int k = 0; k < 6; ++k) { x[k] = mem[(size_t)r*D + lane + 64*k]; s += x[k]*x[k]; }
#pragma unroll
  for (int o = 32; o > 0; o >>= 1) s += __shfl_xor(s, o);
#pragma unroll
  for (int k = 0; k < 6; ++k) {
    unsigned short h = f2bf(x[k]);
    unsigned short l = f2bf(x[k] - bf2f(h));
    mh[(size_t)r*D + lane + 64*k] = h;
    ml[(size_t)r*D + lane + 64*k] = l;
  }
  if (lane == 0) {
    float mn = sqrtf(s);
    float dx = coords[2*r]   - center[0];
    float dy = coords[2*r+1] - center[1];
    float act = 1.0f / (1.0f + sqrtf(dx*dx + dy*dy));
    f2a[r] = make_float2(1.0f / mn, act + 2.0f);
    f2b[r] = make_float2(mn, act);
  }
}

// ---- split-bf16 MFMA sim + per-lane packed top-3 candidates ----
// grid (B/128=8, NC=64), 256 threads = 4 waves (2x2), wave tile 64x64 (mem x query)
__global__ __launch_bounds__(256, 2) void k_sim(
    const unsigned short* __restrict__ qh, const unsigned short* __restrict__ ql,
    const unsigned short* __restrict__ mh, const unsigned short* __restrict__ ml,
    const float2* __restrict__ f2a, unsigned int* __restrict__ keybuf) {
  __shared__ __align__(16) unsigned short sQh[128*32];
  __shared__ __align__(16) unsigned short sQl[128*32];
  __shared__ __align__(16) unsigned short sMh[128*32];
  __shared__ __align__(16) unsigned short sMl[128*32];

  const int tid = threadIdx.x, lane = tid & 63, wave = tid >> 6;
  const int wr = wave >> 1, wc = wave & 1;
  const int t = lane & 15, quad = lane >> 4;
  const int qb = blockIdx.x, nc = blockIdx.y;

  const unsigned short* gsrc;
  unsigned short* ldst;
  if      (wave == 0) { gsrc = qh; ldst = sQh; }
  else if (wave == 1) { gsrc = ql; ldst = sQl; }
  else if (wave == 2) { gsrc = mh; ldst = sMh; }
  else                { gsrc = ml; ldst = sMl; }

  const int srow  = lane >> 2;
  const int skoff = (lane & 3) * 8;

  unsigned int keys[4][3];
#pragma unroll
  for (int j = 0; j < 4; ++j) { keys[j][0] = 0; keys[j][1] = 0; keys[j][2] = 0; }

  for (int mt = 0; mt < 8; ++mt) {
    const size_t mrow0 = (size_t)nc * CHUNK + (size_t)mt * 128;
    const size_t rowbase = (wave < 2) ? (size_t)qb * 128 : mrow0;
    const unsigned short* gb = gsrc + (rowbase + srow) * D + skoff;

    f32x4 acc[4][4];
#pragma unroll
    for (int i = 0; i < 4; ++i)
#pragma unroll
      for (int j = 0; j < 4; ++j) acc[i][j] = (f32x4)0.0f;

    for (int kt = 0; kt < D; kt += 32) {
      __syncthreads();
#pragma unroll
      for (int n = 0; n < 8; ++n)
        async16(gb + (size_t)n * 16 * D + kt, ldst + n * 512 + lane * 8);
      __syncthreads();

      bf16x8 ah[4], al[4], bh[4], bl[4];
#pragma unroll
      for (int i = 0; i < 4; ++i) {
        int ro = (wr*64 + i*16 + t)*32 + quad*8;
        ah[i] = *(const bf16x8*)&sMh[ro];
        al[i] = *(const bf16x8*)&sMl[ro];
        int co = (wc*64 + i*16 + t)*32 + quad*8;
        bh[i] = *(const bf16x8*)&sQh[co];
        bl[i] = *(const bf16x8*)&sQl[co];
      }
#pragma unroll
      for (int i = 0; i < 4; ++i)
#pragma unroll
        for (int j = 0; j < 4; ++j) {
          acc[i][j] = __builtin_amdgcn_mfma_f32_16x16x32_bf16(ah[i], bh[j], acc[i][j], 0, 0, 0);
          acc[i][j] = __builtin_amdgcn_mfma_f32_16x16x32_bf16(ah[i], bl[j], acc[i][j], 0, 0, 0);
          acc[i][j] = __builtin_amdgcn_mfma_f32_16x16x32_bf16(al[i], bh[j], acc[i][j], 0, 0, 0);
        }
    }

    // epilogue: no LDS use; rows = mems, cols = queries
    float invm[16], act2[16]; unsigned int idxv[16];
#pragma unroll
    for (int i = 0; i < 4; ++i)
#pragma unroll
      for (int r = 0; r < 4; ++r) {
        int rl = wr*64 + i*16 + quad*4 + r;
        float2 fa = f2a[mrow0 + rl];
        invm[i*4+r] = fa.x; act2[i*4+r] = fa.y;
        idxv[i*4+r] = (unsigned int)(mt*128 + rl);
      }
#pragma unroll
    for (int j = 0; j < 4; ++j)
#pragma unroll
      for (int i = 0; i < 4; ++i)
#pragma unroll
        for (int r = 0; r < 4; ++r) {
          float v = fmaf(acc[i][j][r], invm[i*4+r], act2[i*4+r]);   // (dot/qn)/mn + act + 2 > 0
          unsigned int key = (__float_as_uint(v) & 0xFFFFFC00u) | idxv[i*4+r];
          insert3b(keys[j], key);
        }
  }

#pragma unroll
  for (int j = 0; j < 4; ++j) {
    int q_local = wc*64 + j*16 + t;
    int c = wr*4 + quad;
    size_t off = ((size_t)(qb*128 + q_local) * NC + nc) * 24 + c*3;
    keybuf[off+0] = keys[j][0];
    keybuf[off+1] = keys[j][1];
    keybuf[off+2] = keys[j][2];
  }
}

// ---- per-query candidate merge + exact fp32 rescore; wave per query ----
__global__ void k_merge(const unsigned int* __restrict__ keybuf,
                        const float* __restrict__ query, const float* __restrict__ memv,
                        const float2* __restrict__ f2b, int* __restrict__ topk) {
  int lane = threadIdx.x & 63, w = threadIdx.x >> 6;
  int q = blockIdx.x * 4 + w;

  // lane <-> chunk: contiguous 24 keys per chunk
  const unsigned int* kb = keybuf + (size_t)q * (NC*24) + lane * 24;
  unsigned int k5[5] = {0,0,0,0,0};
#pragma unroll
  for (int c = 0; c < 6; ++c) {
    uint4 v = *(const uint4*)(kb + c*4);
    insert5b(k5, v.x); insert5b(k5, v.y); insert5b(k5, v.z); insert5b(k5, v.w);
  }

  // tournament: pop global-best 16 times (argmax butterfly)
  int cand[16];
#pragma unroll
  for (int p = 0; p < 16; ++p) {
    unsigned int bk = k5[0]; int blv = lane;
#pragma unroll
    for (int off = 1; off < 64; off <<= 1) {
      unsigned int ok = (unsigned int)__shfl_xor((int)bk, off);
      int ol = __shfl_xor(blv, off);
      if (ok > bk || (ok == bk && ol < blv)) { bk = ok; blv = ol; }
    }
    cand[p] = blv * CHUNK + (int)(bk & 1023u);
    if (lane == blv) { k5[0]=k5[1]; k5[1]=k5[2]; k5[2]=k5[3]; k5[3]=k5[4]; k5[4]=0; }
  }

  // exact fp32 rescore of 16 candidates
  float qv[6]; float sq = 0.f;
#pragma unroll
  for (int k = 0; k < 6; ++k) { qv[k] = query[(size_t)q*D + lane + 64*k]; sq += qv[k]*qv[k]; }
#pragma unroll
  for (int o = 32; o > 0; o >>= 1) sq += __shfl_xor(sq, o);
  float qn = sqrtf(sq);

  float simv[16]; int simi[16];
#pragma unroll
  for (int p = 0; p < 16; ++p) {
    int mi = cand[p];
    float d = 0.f;
#pragma unroll
    for (int k = 0; k < 6; ++k) d += qv[k] * memv[(size_t)mi*D + lane + 64*k];
#pragma unroll
    for (int o = 32; o > 0; o >>= 1) d += __shfl_xor(d, o);
    float2 fb = f2b[mi];
    simv[p] = d / fmaxf(qn * fb.x, FEPS) + fb.y;
    simi[p] = mi;
  }
  if (lane == 0) {
    for (int s = 0; s < KK; ++s) {
      int best = -1; float bv = -1e30f; int bi = 0x7FFFFFFF;
      for (int p = 0; p < 16; ++p) {
        if (simi[p] < 0) continue;
        if (simv[p] > bv || (simv[p] == bv && simi[p] < bi)) { best = p; bv = simv[p]; bi = simi[p]; }
      }
      topk[q*KK + s] = simi[best];
      simi[best] = -1;
    }
  }
}

// ---- fp32 gemm384 (RNN path, unchanged from round 1) ----
template<int ACT, int AMODE, int HASADD>
__global__ __launch_bounds__(256) void k_gemm384(
    const float* __restrict__ A, const float* __restrict__ memv,
    const int* __restrict__ topk,
    const float* __restrict__ W, const float* __restrict__ bias,
    const float* __restrict__ addv, int addstride, int addoff,
    float* __restrict__ C) {
  __shared__ __align__(16) float As2[KT][68];
  __shared__ __align__(16) float Bs2[KT][68];
  int tid = threadIdx.x, tx = tid & 15, ty = tid >> 4;
  int lrow = tid >> 2, lseg = (tid & 3) * 4;
  int rbase = blockIdx.x * 64, hbase = blockIdx.y * 64;

  const float* arow;
  if (AMODE == 0) {
    arow = A + (size_t)(rbase + lrow) * D + lseg;
  } else {
    int r = rbase + lrow; int b = r / 6, t = r - b * 6;
    arow = (t == 0) ? (A + (size_t)b * D + lseg)
                    : (memv + (size_t)topk[b*KK + t - 1] * D + lseg);
  }
  const float* wrow = W + (size_t)(hbase + lrow) * D + lseg;

  float acc[4][4] = {};
  for (int kt = 0; kt < D; kt += KT) {
    float4 a4 = *(const float4*)(arow + kt);
    float4 b4 = *(const float4*)(wrow + kt);
    As2[lseg+0][lrow] = a4.x; As2[lseg+1][lrow] = a4.y;
    As2[lseg+2][lrow] = a4.z; As2[lseg+3][lrow] = a4.w;
    Bs2[lseg+0][lrow] = b4.x; Bs2[lseg+1][lrow] = b4.y;
    Bs2[lseg+2][lrow] = b4.z; Bs2[lseg+3][lrow] = b4.w;
    __syncthreads();
#pragma unroll
    for (int k = 0; k < KT; ++k) {
      float4 a = *(const float4*)&As2[k][ty*4];
      float4 bb = *(const float4*)&Bs2[k][tx*4];
      float av[4] = {a.x, a.y, a.z, a.w};
      float bv[4] = {bb.x, bb.y, bb.z, bb.w};
#pragma unroll
      for (int i = 0; i < 4; ++i)
#pragma unroll
        for (int j = 0; j < 4; ++j)
          acc[i][j] += av[i] * bv[j];
    }
    __syncthreads();
  }
#pragma unroll
  for (int i = 0; i < 4; ++i) {
    int row = rbase + ty*4 + i;
    float vv[4];
#pragma unroll
    for (int j = 0; j < 4; ++j) {
      int h = hbase + tx*4 + j;
      float v = acc[i][j] + bias[h];
      if (HASADD) v += addv[(size_t)row * addstride + addoff + h];
      if (ACT == 1) v = 1.0f / (1.0f + expf(-v));
      else if (ACT == 2) v = tanhf(v);
      vv[j] = v;
    }
    float4 o; o.x = vv[0]; o.y = vv[1]; o.z = vv[2]; o.w = vv[3];
    *(float4*)(C + (size_t)row * H + hbase + tx*4) = o;
  }
}

__global__ void k_h0(const float* __restrict__ xp, const float* __restrict__ bhh,
                     float* __restrict__ hout) {
  int i = blockIdx.x * blockDim.x + threadIdx.x;
  if (i >= B*H) return;
  int b = i / H, h = i - b * H;
  hout[i] = tanhf(xp[(size_t)b * (6*H) + h] + bhh[h]);
}

__global__ void k_out(const float* __restrict__ gate, const float* __restrict__ hfin,
                      const float* __restrict__ xp, float* __restrict__ out) {
  int i = blockIdx.x * blockDim.x + threadIdx.x;
  if (i >= B*H) return;
  int b = i / H, h = i - b * H;
  float g = gate[i];
  out[i] = g * hfin[i] + (1.0f - g) * xp[(size_t)b * (6*H) + h];
}

} // namespace

extern "C" void kernel_launch(void* const* d_in, const int* in_sizes, int n_in,
                              void* d_out, int out_size, void* d_ws, size_t ws_size,
                              hipStream_t stream) {
  const float* query = (const float*)d_in[0];
  const float* memv  = (const float*)d_in[1];
  const float* coords= (const float*)d_in[2];
  const float* sw    = (const float*)d_in[3];
  const float* W_ih  = (const float*)d_in[4];
  const float* b_ih  = (const float*)d_in[5];
  const float* W_hh  = (const float*)d_in[6];
  const float* b_hh  = (const float*)d_in[7];
  const float* W_g   = (const float*)d_in[8];
  const float* b_g   = (const float*)d_in[9];
  float* out = (float*)d_out;

  char* p = (char*)d_ws;
  auto alloc = [&](size_t bytes) {
    char* r = p; p += (bytes + 255) & ~(size_t)255; return r;
  };
  unsigned short* qh = (unsigned short*)alloc((size_t)B * D * 2);
  unsigned short* ql = (unsigned short*)alloc((size_t)B * D * 2);
  unsigned short* mh = (unsigned short*)alloc((size_t)M * D * 2);
  unsigned short* ml = (unsigned short*)alloc((size_t)M * D * 2);
  float2* f2a   = (float2*)alloc((size_t)M * 8);
  float2* f2b   = (float2*)alloc((size_t)M * 8);
  float* center = (float*)alloc(2 * 4);
  unsigned int* keybuf = (unsigned int*)alloc((size_t)B * NC * 24 * 4);
  int*   topk   = (int*)  alloc((size_t)B * KK * 4);
  float* xp     = (float*)alloc((size_t)B * 6 * H * 4);
  float* gate   = (float*)alloc((size_t)B * H * 4);
  float* hA     = (float*)alloc((size_t)B * H * 4);
  float* hB     = (float*)alloc((size_t)B * H * 4);

  k_center<<<1, 64, 0, stream>>>(sw, center);
  k_prep_q<<<B/4, 256, 0, stream>>>(query, qh, ql);
  k_prep_m<<<M/4, 256, 0, stream>>>(memv, coords, center, mh, ml, f2a, f2b);
  k_sim<<<dim3(B/128, NC), 256, 0, stream>>>(qh, ql, mh, ml, f2a, keybuf);
  k_merge<<<B/4, 256, 0, stream>>>(keybuf, query, memv, f2b, topk);

  k_gemm384<0,1,0><<<dim3(B*6/64, H/64), 256, 0, stream>>>(
      query, memv, topk, W_ih, b_ih, nullptr, 0, 0, xp);
  k_gemm384<1,0,0><<<dim3(B/64, H/64), 256, 0, stream>>>(
      query, nullptr, nullptr, W_g, b_g, nullptr, 0, 0, gate);

  k_h0<<<(B*H + 255)/256, 256, 0, stream>>>(xp, b_hh, hA);
  float* hcur = hA; float* hnxt = hB;
  for (int t = 1; t < 6; ++t) {
    k_gemm384<2,0,1><<<dim3(B/64, H/64), 256, 0, stream>>>(
        hcur, nullptr, nullptr, W_hh, b_hh, xp, 6*H, t*H, hnxt);
    float* tmp = hcur; hcur = hnxt; hnxt = tmp;
  }
  k_out<<<(B*H + 255)/256, 256, 0, stream>>>(gate, hcur, xp, out);
}

// Round 3
// 425.072 us; speedup vs baseline: 2.9442x; 1.3034x over previous
//
#include <hip/hip_runtime.h>
#include <math.h>

namespace {

typedef float f32x4 __attribute__((ext_vector_type(4)));
typedef short bf16x8 __attribute__((ext_vector_type(8)));
typedef unsigned short ushort_t;

constexpr int B  = 1024;
constexpr int M  = 65536;
constexpr int D  = 384;
constexpr int H  = 384;
constexpr int KK = 5;
constexpr int NC = 128;         // chunks over M
constexpr int CHUNK = M / NC;   // 512 mems per chunk
constexpr float FEPS = 1e-8f;

__device__ __forceinline__ ushort_t f2bf(float x) {
  unsigned int u = __float_as_uint(x);
  unsigned int r = (u + 0x7FFFu + ((u >> 16) & 1u)) >> 16;   // RNE
  return (ushort_t)r;
}
__device__ __forceinline__ float bf2f(ushort_t h) {
  return __uint_as_float(((unsigned int)h) << 16);
}

__device__ __forceinline__ void async16(const ushort_t* g, ushort_t* l) {
  __builtin_amdgcn_global_load_lds(
      (const __attribute__((address_space(1))) unsigned int*)g,
      (__attribute__((address_space(3))) unsigned int*)l, 16, 0, 0);
}

__device__ __forceinline__ void insert3b(unsigned int* k, unsigned int v) {
  unsigned int t0 = min(k[0], v); k[0] = max(k[0], v);
  unsigned int t1 = min(k[1], t0); k[1] = max(k[1], t0);
  k[2] = max(k[2], t1);
}
__device__ __forceinline__ void insert5b(unsigned int* k, unsigned int v) {
  unsigned int t0 = min(k[0], v); k[0] = max(k[0], v);
  unsigned int t1 = min(k[1], t0); k[1] = max(k[1], t0);
  unsigned int t2 = min(k[2], t1); k[2] = max(k[2], t1);
  unsigned int t3 = min(k[3], t2); k[3] = max(k[3], t2);
  k[4] = max(k[4], t3);
}

// ================= mega prep: mem split+stats | q splits | weight splits ====
__global__ __launch_bounds__(256) void k_prep(
    const float* __restrict__ q, const float* __restrict__ mem,
    const float* __restrict__ coords, const float* __restrict__ sw,
    const float* __restrict__ W_ih, const float* __restrict__ W_hh,
    const float* __restrict__ W_g,
    ushort_t* __restrict__ qh, ushort_t* __restrict__ qrh, ushort_t* __restrict__ qrl,
    ushort_t* __restrict__ mh, ushort_t* __restrict__ ml,
    float2* __restrict__ f2a, float2* __restrict__ f2b,
    ushort_t* __restrict__ wihh, ushort_t* __restrict__ wihl,
    ushort_t* __restrict__ whhh, ushort_t* __restrict__ whhl,
    ushort_t* __restrict__ wgh, ushort_t* __restrict__ wgl) {
  int wv = threadIdx.x >> 6, lane = threadIdx.x & 63;
  int bid = blockIdx.x;
  if (bid < M/4) {
    int r = bid*4 + wv;
    // center (per-wave, broadcast via xor-reduce)
    float cx = 0.f, cy = 0.f;
    for (int i = lane; i < H; i += 64) { cx += sw[2*i]; cy += sw[2*i+1]; }
#pragma unroll
    for (int o = 32; o > 0; o >>= 1) { cx += __shfl_xor(cx, o); cy += __shfl_xor(cy, o); }
    cx *= (1.0f/384.0f); cy *= (1.0f/384.0f);
    float x[6]; float s = 0.f;
#pragma unroll
    for (int k = 0; k < 6; ++k) { x[k] = mem[(size_t)r*D + lane + 64*k]; s += x[k]*x[k]; }
#pragma unroll
    for (int o = 32; o > 0; o >>= 1) s += __shfl_xor(s, o);
#pragma unroll
    for (int k = 0; k < 6; ++k) {
      ushort_t h = f2bf(x[k]);
      mh[(size_t)r*D + lane + 64*k] = h;
      ml[(size_t)r*D + lane + 64*k] = f2bf(x[k] - bf2f(h));
    }
    if (lane == 0) {
      float mn = sqrtf(s);
      float dx = coords[2*r] - cx, dy = coords[2*r+1] - cy;
      float act = 1.0f / (1.0f + sqrtf(dx*dx + dy*dy));
      f2a[r] = make_float2(1.0f / mn, act + 2.0f);
      f2b[r] = make_float2(mn, act);
    }
  } else if (bid < M/4 + B/4) {
    int r = (bid - M/4)*4 + wv;
    float x[6]; float s = 0.f;
#pragma unroll
    for (int k = 0; k < 6; ++k) { x[k] = q[(size_t)r*D + lane + 64*k]; s += x[k]*x[k]; }
#pragma unroll
    for (int o = 32; o > 0; o >>= 1) s += __shfl_xor(s, o);
    float inv = 1.0f / sqrtf(s);
#pragma unroll
    for (int k = 0; k < 6; ++k) {
      ushort_t rh = f2bf(x[k]);
      qrh[(size_t)r*D + lane + 64*k] = rh;
      qrl[(size_t)r*D + lane + 64*k] = f2bf(x[k] - bf2f(rh));
      qh [(size_t)r*D + lane + 64*k] = f2bf(x[k] * inv);   // normalized hi only
    }
  } else {
    int r = (bid - M/4 - B/4)*4 + wv;   // 0..1151
    const float* src; ushort_t* dh; ushort_t* dl;
    if (r < 384)      { src = W_ih + (size_t)r*D;       dh = wihh + (size_t)r*D;       dl = wihl + (size_t)r*D; }
    else if (r < 768) { src = W_hh + (size_t)(r-384)*D; dh = whhh + (size_t)(r-384)*D; dl = whhl + (size_t)(r-384)*D; }
    else              { src = W_g  + (size_t)(r-768)*D; dh = wgh  + (size_t)(r-768)*D; dl = wgl  + (size_t)(r-768)*D; }
#pragma unroll
    for (int k = 0; k < 6; ++k) {
      float v = src[lane + 64*k];
      ushort_t h = f2bf(v);
      dh[lane + 64*k] = h;
      dl[lane + 64*k] = f2bf(v - bf2f(h));
    }
  }
}

// ================= sim: 2-term split-bf16 MFMA + per-lane top-3 ============
// grid (B/128=8, NC=128), 256 threads = 4 waves (2x2), wave tile 64m x 64q
__global__ __launch_bounds__(256, 2) void k_sim(
    const ushort_t* __restrict__ qh,
    const ushort_t* __restrict__ mh, const ushort_t* __restrict__ ml,
    const float2* __restrict__ f2a, unsigned int* __restrict__ keybuf) {
  __shared__ __align__(16) ushort_t sQh[128*32];
  __shared__ __align__(16) ushort_t sMh[128*32];
  __shared__ __align__(16) ushort_t sMl[128*32];

  const int tid = threadIdx.x, lane = tid & 63, wave = tid >> 6;
  const int wr = wave >> 1, wc = wave & 1;
  const int t = lane & 15, quad = lane >> 4;
  const int qb = blockIdx.x, nc = blockIdx.y;
  const int rowoff = lane >> 2, koff = (lane & 3) * 8;
  const size_t qrow0 = (size_t)qb * 128;

  unsigned int keys[4][3];
#pragma unroll
  for (int j = 0; j < 4; ++j) { keys[j][0] = 0; keys[j][1] = 0; keys[j][2] = 0; }

  for (int mt = 0; mt < 4; ++mt) {
    const size_t mrow0 = (size_t)nc * CHUNK + (size_t)mt * 128;
    f32x4 acc[4][4];
#pragma unroll
    for (int i = 0; i < 4; ++i)
#pragma unroll
      for (int j = 0; j < 4; ++j) acc[i][j] = (f32x4)0.0f;

    for (int kt = 0; kt < D; kt += 32) {
      __syncthreads();
#pragma unroll
      for (int n = 0; n < 6; ++n) {
        int f = wave*6 + n; int arr = f >> 3, slot = f & 7;
        const ushort_t* src = arr == 0 ? qh : (arr == 1 ? mh : ml);
        ushort_t* dst = arr == 0 ? sQh : (arr == 1 ? sMh : sMl);
        size_t rowb = arr == 0 ? qrow0 : mrow0;
        async16(src + (rowb + slot*16 + rowoff)*D + kt + koff,
                dst + slot*512 + lane*8);
      }
      __syncthreads();

      bf16x8 ah[4], al[4], bh[4];
#pragma unroll
      for (int i = 0; i < 4; ++i) {
        int ro = (wr*64 + i*16 + t)*32 + quad*8;
        ah[i] = *(const bf16x8*)&sMh[ro];
        al[i] = *(const bf16x8*)&sMl[ro];
        int co = (wc*64 + i*16 + t)*32 + quad*8;
        bh[i] = *(const bf16x8*)&sQh[co];
      }
#pragma unroll
      for (int i = 0; i < 4; ++i)
#pragma unroll
        for (int j = 0; j < 4; ++j) {
          acc[i][j] = __builtin_amdgcn_mfma_f32_16x16x32_bf16(ah[i], bh[j], acc[i][j], 0, 0, 0);
          acc[i][j] = __builtin_amdgcn_mfma_f32_16x16x32_bf16(al[i], bh[j], acc[i][j], 0, 0, 0);
        }
    }

    float invm[16], act2[16]; unsigned int idxv[16];
#pragma unroll
    for (int i = 0; i < 4; ++i)
#pragma unroll
      for (int r = 0; r < 4; ++r) {
        int rl = wr*64 + i*16 + quad*4 + r;
        float2 fa = f2a[mrow0 + rl];
        invm[i*4+r] = fa.x; act2[i*4+r] = fa.y;
        idxv[i*4+r] = (unsigned int)(((nc & 1) << 9) | (mt*128 + rl));
      }
#pragma unroll
    for (int j = 0; j < 4; ++j)
#pragma unroll
      for (int i = 0; i < 4; ++i)
#pragma unroll
        for (int r = 0; r < 4; ++r) {
          float v = fmaf(acc[i][j][r], invm[i*4+r], act2[i*4+r]);
          unsigned int key = (__float_as_uint(v) & 0xFFFFFC00u) | idxv[i*4+r];
          insert3b(keys[j], key);
        }
  }

#pragma unroll
  for (int j = 0; j < 4; ++j) {
    int q_local = wc*64 + j*16 + t;
    int c = wr*4 + quad;
    size_t off = ((size_t)(qb*128 + q_local) * NC + nc) * 24 + c*3;
    keybuf[off+0] = keys[j][0];
    keybuf[off+1] = keys[j][1];
    keybuf[off+2] = keys[j][2];
  }
}

// ============ merge candidates + exact fp32 rescore; wave per query =========
__global__ void k_merge(const unsigned int* __restrict__ keybuf,
                        const float* __restrict__ query, const float* __restrict__ memv,
                        const float2* __restrict__ f2b, int* __restrict__ topk) {
  int lane = threadIdx.x & 63, w = threadIdx.x >> 6;
  int q = blockIdx.x * 4 + w;

  // lane covers chunks 2*lane, 2*lane+1: 48 contiguous keys
  const unsigned int* kb = keybuf + (size_t)q * (NC*24) + (size_t)lane * 48;
  unsigned int k5[5] = {0,0,0,0,0};
#pragma unroll
  for (int c = 0; c < 12; ++c) {
    uint4 v = *(const uint4*)(kb + c*4);
    insert5b(k5, v.x); insert5b(k5, v.y); insert5b(k5, v.z); insert5b(k5, v.w);
  }

  int cand[16];
#pragma unroll
  for (int p = 0; p < 16; ++p) {
    unsigned int bk = k5[0]; int blv = lane;
#pragma unroll
    for (int off = 1; off < 64; off <<= 1) {
      unsigned int ok = (unsigned int)__shfl_xor((int)bk, off);
      int ol = __shfl_xor(blv, off);
      if (ok > bk || (ok == bk && ol < blv)) { bk = ok; blv = ol; }
    }
    cand[p] = (blv << 10) | (int)(bk & 1023u);
    if (lane == blv) { k5[0]=k5[1]; k5[1]=k5[2]; k5[2]=k5[3]; k5[3]=k5[4]; k5[4]=0; }
  }

  float qv[6]; float sq = 0.f;
#pragma unroll
  for (int k = 0; k < 6; ++k) { qv[k] = query[(size_t)q*D + lane + 64*k]; sq += qv[k]*qv[k]; }
#pragma unroll
  for (int o = 32; o > 0; o >>= 1) sq += __shfl_xor(sq, o);
  float qn = sqrtf(sq);

  float simv[16]; int simi[16];
#pragma unroll
  for (int p = 0; p < 16; ++p) {
    int mi = cand[p];
    float d = 0.f;
#pragma unroll
    for (int k = 0; k < 6; ++k) d += qv[k] * memv[(size_t)mi*D + lane + 64*k];
#pragma unroll
    for (int o = 32; o > 0; o >>= 1) d += __shfl_xor(d, o);
    float2 fb = f2b[mi];
    simv[p] = d / fmaxf(qn * fb.x, FEPS) + fb.y;
    simi[p] = mi;
  }
  if (lane == 0) {
    for (int s = 0; s < KK; ++s) {
      int best = -1; float bv = -1e30f; int bi = 0x7FFFFFFF;
      for (int p = 0; p < 16; ++p) {
        if (simi[p] < 0) continue;
        if (simv[p] > bv || (simv[p] == bv && simi[p] < bi)) { best = p; bv = simv[p]; bi = simi[p]; }
      }
      topk[q*KK + s] = simi[best];
      simi[best] = -1;
    }
  }
}

// ===== tail1: x_proj (gathered, 96 row-tiles) + gate (16 row-tiles) + h1 ====
// grid (112, 6); 64x64 tile, K=384 in 3 rounds of 4x32 subtiles; 3-term split
__global__ __launch_bounds__(256) void k_tail1(
    const ushort_t* __restrict__ qrh, const ushort_t* __restrict__ qrl,
    const ushort_t* __restrict__ mh, const ushort_t* __restrict__ ml,
    const int* __restrict__ topk,
    const ushort_t* __restrict__ wihh, const ushort_t* __restrict__ wihl,
    const ushort_t* __restrict__ wgh, const ushort_t* __restrict__ wgl,
    const float* __restrict__ b_ih, const float* __restrict__ b_hh,
    const float* __restrict__ b_g,
    float* __restrict__ xp, float* __restrict__ gate,
    ushort_t* __restrict__ hoh, ushort_t* __restrict__ hol) {
  __shared__ __align__(16) ushort_t sAh[64*128];
  __shared__ __align__(16) ushort_t sAl[64*128];
  __shared__ __align__(16) ushort_t sWh[64*128];
  __shared__ __align__(16) ushort_t sWl[64*128];

  const int tid = threadIdx.x, lane = tid & 63, wave = tid >> 6;
  const int wr = wave >> 1, wc = wave & 1;
  const int t = lane & 15, quad = lane >> 4;
  const bool xmode = blockIdx.x < 96;
  const int cbase = blockIdx.y * 64;
  const int rowoff = lane >> 2, koff = (lane & 3) * 8;

  const ushort_t* gp[4];
  if (wave < 2) {
#pragma unroll
    for (int slot = 0; slot < 4; ++slot) {
      int rl = slot*16 + rowoff;
      const ushort_t* src;
      if (xmode) {
        int g = blockIdx.x*64 + rl;
        int b = g / 6, tt = g - b*6;
        if (tt == 0) src = (wave == 0 ? qrh : qrl) + (size_t)b * D;
        else         src = (wave == 0 ? mh  : ml ) + (size_t)topk[b*KK + tt - 1] * D;
      } else {
        int rq = (blockIdx.x - 96)*64 + rl;
        src = (wave == 0 ? qrh : qrl) + (size_t)rq * D;
      }
      gp[slot] = src + koff;
    }
  } else {
#pragma unroll
    for (int slot = 0; slot < 4; ++slot) {
      int rl = slot*16 + rowoff;
      const ushort_t* wsrc = xmode ? (wave == 2 ? wihh : wihl)
                                   : (wave == 2 ? wgh  : wgl);
      gp[slot] = wsrc + (size_t)(cbase + rl) * D + koff;
    }
  }
  ushort_t* ldst = (wave == 0) ? sAh : (wave == 1) ? sAl : (wave == 2) ? sWh : sWl;

  f32x4 acc[2][2];
#pragma unroll
  for (int i = 0; i < 2; ++i)
#pragma unroll
    for (int j = 0; j < 2; ++j) acc[i][j] = (f32x4)0.0f;

  for (int r3 = 0; r3 < 3; ++r3) {
    __syncthreads();
#pragma unroll
    for (int s = 0; s < 4; ++s)
#pragma unroll
      for (int slot = 0; slot < 4; ++slot)
        async16(gp[slot] + r3*128 + s*32, ldst + s*2048 + slot*512 + lane*8);
    __syncthreads();
#pragma unroll
    for (int s = 0; s < 4; ++s) {
      bf16x8 ah[2], al[2], bh[2], bl[2];
#pragma unroll
      for (int i = 0; i < 2; ++i) {
        int ro = s*2048 + (wr*32 + i*16 + t)*32 + quad*8;
        ah[i] = *(const bf16x8*)&sAh[ro];
        al[i] = *(const bf16x8*)&sAl[ro];
        int co = s*2048 + (wc*32 + i*16 + t)*32 + quad*8;
        bh[i] = *(const bf16x8*)&sWh[co];
        bl[i] = *(const bf16x8*)&sWl[co];
      }
#pragma unroll
      for (int i = 0; i < 2; ++i)
#pragma unroll
        for (int j = 0; j < 2; ++j) {
          acc[i][j] = __builtin_amdgcn_mfma_f32_16x16x32_bf16(ah[i], bh[j], acc[i][j], 0, 0, 0);
          acc[i][j] = __builtin_amdgcn_mfma_f32_16x16x32_bf16(ah[i], bl[j], acc[i][j], 0, 0, 0);
          acc[i][j] = __builtin_amdgcn_mfma_f32_16x16x32_bf16(al[i], bh[j], acc[i][j], 0, 0, 0);
        }
    }
  }

#pragma unroll
  for (int i = 0; i < 2; ++i)
#pragma unroll
    for (int j = 0; j < 2; ++j)
#pragma unroll
      for (int r = 0; r < 4; ++r) {
        int rloc = wr*32 + i*16 + quad*4 + r;
        int h = cbase + wc*32 + j*16 + t;
        float a = acc[i][j][r];
        if (xmode) {
          int g = blockIdx.x*64 + rloc;
          float v = a + b_ih[h];
          xp[(size_t)g*H + h] = v;
          int b = g / 6;
          if (g - b*6 == 0) {
            float hv = tanhf(v + b_hh[h]);
            ushort_t hi = f2bf(hv);
            hoh[(size_t)b*H + h] = hi;
            hol[(size_t)b*H + h] = f2bf(hv - bf2f(hi));
          }
        } else {
          int rq = (blockIdx.x - 96)*64 + rloc;
          gate[(size_t)rq*H + h] = 1.0f / (1.0f + expf(-(a + b_g[h])));
        }
      }
}

// ================= RNN step: h' = tanh(x_t + h @ W_hh^T + b_hh) =============
// grid (16, 6); LAST fuses the gated output blend
template<int LAST>
__global__ __launch_bounds__(256) void k_rnn(
    const ushort_t* __restrict__ hih, const ushort_t* __restrict__ hil,
    const ushort_t* __restrict__ whhh, const ushort_t* __restrict__ whhl,
    const float* __restrict__ b_hh, const float* __restrict__ xp,
    const float* __restrict__ gate, int step,
    ushort_t* __restrict__ hoh, ushort_t* __restrict__ hol,
    float* __restrict__ out) {
  __shared__ __align__(16) ushort_t sAh[64*128];
  __shared__ __align__(16) ushort_t sAl[64*128];
  __shared__ __align__(16) ushort_t sWh[64*128];
  __shared__ __align__(16) ushort_t sWl[64*128];

  const int tid = threadIdx.x, lane = tid & 63, wave = tid >> 6;
  const int wr = wave >> 1, wc = wave & 1;
  const int t = lane & 15, quad = lane >> 4;
  const int rbase = blockIdx.x * 64, cbase = blockIdx.y * 64;
  const int rowoff = lane >> 2, koff = (lane & 3) * 8;

  const ushort_t* gp[4];
#pragma unroll
  for (int slot = 0; slot < 4; ++slot) {
    int rl = slot*16 + rowoff;
    const ushort_t* src =
        (wave == 0) ? hih + (size_t)(rbase + rl)*D :
        (wave == 1) ? hil + (size_t)(rbase + rl)*D :
        (wave == 2) ? whhh + (size_t)(cbase + rl)*D :
                      whhl + (size_t)(cbase + rl)*D;
    gp[slot] = src + koff;
  }
  ushort_t* ldst = (wave == 0) ? sAh : (wave == 1) ? sAl : (wave == 2) ? sWh : sWl;

  f32x4 acc[2][2];
#pragma unroll
  for (int i = 0; i < 2; ++i)
#pragma unroll
    for (int j = 0; j < 2; ++j) acc[i][j] = (f32x4)0.0f;

  for (int r3 = 0; r3 < 3; ++r3) {
    __syncthreads();
#pragma unroll
    for (int s = 0; s < 4; ++s)
#pragma unroll
      for (int slot = 0; slot < 4; ++slot)
        async16(gp[slot] + r3*128 + s*32, ldst + s*2048 + slot*512 + lane*8);
    __syncthreads();
#pragma unroll
    for (int s = 0; s < 4; ++s) {
      bf16x8 ah[2], al[2], bh[2], bl[2];
#pragma unroll
      for (int i = 0; i < 2; ++i) {
        int ro = s*2048 + (wr*32 + i*16 + t)*32 + quad*8;
        ah[i] = *(const bf16x8*)&sAh[ro];
        al[i] = *(const bf16x8*)&sAl[ro];
        int co = s*2048 + (wc*32 + i*16 + t)*32 + quad*8;
        bh[i] = *(const bf16x8*)&sWh[co];
        bl[i] = *(const bf16x8*)&sWl[co];
      }
#pragma unroll
      for (int i = 0; i < 2; ++i)
#pragma unroll
        for (int j = 0; j < 2; ++j) {
          acc[i][j] = __builtin_amdgcn_mfma_f32_16x16x32_bf16(ah[i], bh[j], acc[i][j], 0, 0, 0);
          acc[i][j] = __builtin_amdgcn_mfma_f32_16x16x32_bf16(ah[i], bl[j], acc[i][j], 0, 0, 0);
          acc[i][j] = __builtin_amdgcn_mfma_f32_16x16x32_bf16(al[i], bh[j], acc[i][j], 0, 0, 0);
        }
    }
  }

#pragma unroll
  for (int i = 0; i < 2; ++i)
#pragma unroll
    for (int j = 0; j < 2; ++j)
#pragma unroll
      for (int r = 0; r < 4; ++r) {
        int row = rbase + wr*32 + i*16 + quad*4 + r;
        int h = cbase + wc*32 + j*16 + t;
        float v = acc[i][j][r] + b_hh[h] + xp[(size_t)row*(6*H) + step*H + h];
        float hv = tanhf(v);
        if (LAST) {
          float g = gate[(size_t)row*H + h];
          out[(size_t)row*H + h] = g*hv + (1.0f - g)*xp[(size_t)row*(6*H) + h];
        } else {
          ushort_t hi = f2bf(hv);
          hoh[(size_t)row*H + h] = hi;
          hol[(size_t)row*H + h] = f2bf(hv - bf2f(hi));
        }
      }
}

} // namespace

extern "C" void kernel_launch(void* const* d_in, const int* in_sizes, int n_in,
                              void* d_out, int out_size, void* d_ws, size_t ws_size,
                              hipStream_t stream) {
  const float* query = (const float*)d_in[0];
  const float* memv  = (const float*)d_in[1];
  const float* coords= (const float*)d_in[2];
  const float* sw    = (const float*)d_in[3];
  const float* W_ih  = (const float*)d_in[4];
  const float* b_ih  = (const float*)d_in[5];
  const float* W_hh  = (const float*)d_in[6];
  const float* b_hh  = (const float*)d_in[7];
  const float* W_g   = (const float*)d_in[8];
  const float* b_g   = (const float*)d_in[9];
  float* out = (float*)d_out;

  char* p = (char*)d_ws;
  auto alloc = [&](size_t bytes) {
    char* r = p; p += (bytes + 255) & ~(size_t)255; return r;
  };
  ushort_t* qh  = (ushort_t*)alloc((size_t)B * D * 2);
  ushort_t* qrh = (ushort_t*)alloc((size_t)B * D * 2);
  ushort_t* qrl = (ushort_t*)alloc((size_t)B * D * 2);
  ushort_t* mh  = (ushort_t*)alloc((size_t)M * D * 2);
  ushort_t* ml  = (ushort_t*)alloc((size_t)M * D * 2);
  float2* f2a   = (float2*)alloc((size_t)M * 8);
  float2* f2b   = (float2*)alloc((size_t)M * 8);
  ushort_t* wihh = (ushort_t*)alloc((size_t)H * D * 2);
  ushort_t* wihl = (ushort_t*)alloc((size_t)H * D * 2);
  ushort_t* whhh = (ushort_t*)alloc((size_t)H * D * 2);
  ushort_t* whhl = (ushort_t*)alloc((size_t)H * D * 2);
  ushort_t* wgh  = (ushort_t*)alloc((size_t)H * D * 2);
  ushort_t* wgl  = (ushort_t*)alloc((size_t)H * D * 2);
  unsigned int* keybuf = (unsigned int*)alloc((size_t)B * NC * 24 * 4);
  int*   topk   = (int*)alloc((size_t)B * KK * 4);
  float* xp     = (float*)alloc((size_t)B * 6 * H * 4);
  float* gate   = (float*)alloc((size_t)B * H * 4);
  ushort_t* hAh = (ushort_t*)alloc((size_t)B * H * 2);
  ushort_t* hAl = (ushort_t*)alloc((size_t)B * H * 2);
  ushort_t* hBh = (ushort_t*)alloc((size_t)B * H * 2);
  ushort_t* hBl = (ushort_t*)alloc((size_t)B * H * 2);

  k_prep<<<M/4 + B/4 + 288, 256, 0, stream>>>(
      query, memv, coords, sw, W_ih, W_hh, W_g,
      qh, qrh, qrl, mh, ml, f2a, f2b,
      wihh, wihl, whhh, whhl, wgh, wgl);
  k_sim<<<dim3(B/128, NC), 256, 0, stream>>>(qh, mh, ml, f2a, keybuf);
  k_merge<<<B/4, 256, 0, stream>>>(keybuf, query, memv, f2b, topk);
  k_tail1<<<dim3(112, 6), 256, 0, stream>>>(
      qrh, qrl, mh, ml, topk, wihh, wihl, wgh, wgl,
      b_ih, b_hh, b_g, xp, gate, hAh, hAl);
  k_rnn<0><<<dim3(16, 6), 256, 0, stream>>>(hAh, hAl, whhh, whhl, b_hh, xp, gate, 1, hBh, hBl, out);
  k_rnn<0><<<dim3(16, 6), 256, 0, stream>>>(hBh, hBl, whhh, whhl, b_hh, xp, gate, 2, hAh, hAl, out);
  k_rnn<0><<<dim3(16, 6), 256, 0, stream>>>(hAh, hAl, whhh, whhl, b_hh, xp, gate, 3, hBh, hBl, out);
  k_rnn<0><<<dim3(16, 6), 256, 0, stream>>>(hBh, hBl, whhh, whhl, b_hh, xp, gate, 4, hAh, hAl, out);
  k_rnn<1><<<dim3(16, 6), 256, 0, stream>>>(hAh, hAl, whhh, whhl, b_hh, xp, gate, 5, hBh, hBl, out);
}